// Round 10
// baseline (176.433 us; speedup 1.0000x reference)
//
#include <hip/hip_runtime.h>
#include <stdint.h>

// OctonionLinear == GEMM: out[b, i*8+k] = sum_{j,p} x[b, j*8+p] * W[i,j,p,k] + bias[i,k]
// M=512, N=4096, K=4096, fp32 in/out, bf16 MFMA.
// R17 == R15/R16 resubmit. R15 died to acquisition infra; R16 SIGABRT'd on a
//  container that took 625s to push a 70MB file (unhealthy). Full line audit
//  found no OOB/race/alignment fault (W max idx 16,777,215 = last elem; LDS
//  writes end exactly at 16KB buffer boundary; dbuf barrier discipline OK).
//  Precedent: R8/R9 infra-failed, identical R10 then passed. Pre-commit: a
//  second SIGABRT on this source = real fault -> revert to R12 next round.
// R15: FULL FUSION — delete the prep kernel. R14 proved traffic costs are the
//  only reliably-visible deltas (KSPLIT=8 = +64MB = +10us measured); gemm at
//  2 blocks/CU is drain-pinned at ~45us regardless of schedule. So cut the
//  bt round-trip (W 64r + bt 32w + 32r) and abf (8r+4w+4r): gemm reg-stages
//  BOTH operands from native fp32 with in-register bf16 cvt + swizzled
//  ds_write (T14 pattern; swizzle on write AND read, rule #21).
//  W[i][j][p][k]: dwordx2 over (k,k+1) x 8 p's = rows (n,n+1) of one kg-chunk.
//  x: already kg-contiguous, 4x dwordx4 per thread.
//  2 launches: fused gemm (KSPLIT=4, 128x128, swizzled, part) + reduce.
//  Traffic: 226MB (R12 3-kernel path) -> 144MB. ws = part 32MB only.

#define M_DIM 512
#define N_DIM 4096
#define K_DIM 4096
#define KSPLIT 4
#define KC (K_DIM / KSPLIT)         // 1024
#define NIT (KC / 32)               // 32
#define PART_ELEMS (M_DIM * N_DIM)  // 2097152 floats per z-slice

typedef __bf16 bf16x8 __attribute__((ext_vector_type(8)));
typedef float f32x4 __attribute__((ext_vector_type(4)));

// fallback-only: out = bias broadcast before atomic accumulation
__global__ __launch_bounds__(256) void bias_init_kernel(
    const float* __restrict__ bias, float* __restrict__ out) {
  int g = blockIdx.x * 256 + threadIdx.x;  // [0, 524288)
  int el = g * 4;
  int col = el & (N_DIM - 1);
  *(float4*)(out + el) = *(const float4*)(bias + col);
}

// Tile 128M x 128N, BK=32, 256 threads = 4 waves, wave-tile 64M x 64N (4x4).
// LDS per buffer: A 128x32 bf16 @0 (8KB), B 128x32 bf16 @8KB; dbuf = 32KB.
// Swizzle (R12-verified, conflicts=0 on reads): row r's 16B slot
// l = (g + (r>>1)) & 3 holds global kg-chunk g. Applied on WRITE and READ.
__global__ __launch_bounds__(256) void gemm_kernel(
    const float* __restrict__ X, const float* __restrict__ W,
    float* __restrict__ out, float* __restrict__ part, int use_atomic) {
  __shared__ __align__(16) char lds[2][16 * 1024];
  const int t = threadIdx.x;
  const int n0 = blockIdx.x * 128;
  const int m0 = blockIdx.y * 128;
  const int z = blockIdx.z;
  const int kc0 = z * KC;
  const int w = t >> 6;
  const int lane = t & 63;
  const int wr = w >> 1;     // 0..1 -> 64 M-rows
  const int wc = w & 1;      // 0..1 -> 64 N-cols
  const int lrow = lane & 15;
  const int kb = lane >> 4;  // k-block 0..3 (8 bf16 each)
  // read slot: (row>>1)&3 == (lrow>>1)&3 since wr*64, mt*16 are 0 mod 8 rows
  const int kslot = (kb + (lrow >> 1)) & 3;

  f32x4 acc[4][4] = {};

  // ---- A staging (x fp32, kg-contiguous): thread -> row t>>1, 2 granules
  const int arow = t >> 1;        // 0..127
  const int ag0 = (t & 1) * 2;    // granule 0 or 2 (8 floats each)
  const float* aBase = X + (size_t)(m0 + arow) * K_DIM + kc0 + ag0 * 8;
  const int as0 = (ag0 + (arow >> 1)) & 3;
  const int as1 = (ag0 + 1 + (arow >> 1)) & 3;
  const int awOff0 = arow * 64 + as0 * 16;  // bytes within A region
  const int awOff1 = arow * 64 + as1 * 16;

  // ---- B staging (W fp32 native [i][j][p][k]): thread -> rows (rr, rr+1),
  // one kg-chunk jj. dwordx2 over (k,k+1), p = 0..7.
  const int a2 = t >> 2;  // 0..63 row-pair index
  const int jj = t & 3;   // kg-chunk within BK=32
  const int rr = a2 * 2;  // even relative row
  const int nrow = n0 + rr;
  const int iW = nrow >> 3;
  const int kW = nrow & 7;  // even
  const float* wBase =
      W + (size_t)iW * 32768 + (size_t)((kc0 >> 3) + jj) * 64 + kW;
  const int bslot = (jj + a2) & 3;                 // a2 == rr>>1
  const int bwOff = 8192 + rr * 64 + bslot * 16;   // bytes within buffer

  float4 av0, av1, av2, av3;
  float2 bv0, bv1, bv2, bv3, bv4, bv5, bv6, bv7;

  auto loadA = [&](int it) {
    const float* p = aBase + it * 32;
    av0 = *(const float4*)(p);
    av1 = *(const float4*)(p + 4);
    av2 = *(const float4*)(p + 8);
    av3 = *(const float4*)(p + 12);
  };
  auto loadB = [&](int it) {
    const float* p = wBase + it * 256;  // j advances 4 per iter (4*64 floats)
    bv0 = *(const float2*)(p);
    bv1 = *(const float2*)(p + 8);
    bv2 = *(const float2*)(p + 16);
    bv3 = *(const float2*)(p + 24);
    bv4 = *(const float2*)(p + 32);
    bv5 = *(const float2*)(p + 40);
    bv6 = *(const float2*)(p + 48);
    bv7 = *(const float2*)(p + 56);
  };
  auto writeA = [&](int it) {
    char* buf = lds[it & 1];
    bf16x8 r0, r1;
    r0[0] = (__bf16)av0.x; r0[1] = (__bf16)av0.y;
    r0[2] = (__bf16)av0.z; r0[3] = (__bf16)av0.w;
    r0[4] = (__bf16)av1.x; r0[5] = (__bf16)av1.y;
    r0[6] = (__bf16)av1.z; r0[7] = (__bf16)av1.w;
    r1[0] = (__bf16)av2.x; r1[1] = (__bf16)av2.y;
    r1[2] = (__bf16)av2.z; r1[3] = (__bf16)av2.w;
    r1[4] = (__bf16)av3.x; r1[5] = (__bf16)av3.y;
    r1[6] = (__bf16)av3.z; r1[7] = (__bf16)av3.w;
    *(bf16x8*)(buf + awOff0) = r0;
    *(bf16x8*)(buf + awOff1) = r1;
  };
  auto writeB = [&](int it) {
    char* buf = lds[it & 1];
    bf16x8 r0, r1;  // r0: row rr (k=kW), r1: row rr+1 (k=kW+1)
    r0[0] = (__bf16)bv0.x; r1[0] = (__bf16)bv0.y;
    r0[1] = (__bf16)bv1.x; r1[1] = (__bf16)bv1.y;
    r0[2] = (__bf16)bv2.x; r1[2] = (__bf16)bv2.y;
    r0[3] = (__bf16)bv3.x; r1[3] = (__bf16)bv3.y;
    r0[4] = (__bf16)bv4.x; r1[4] = (__bf16)bv4.y;
    r0[5] = (__bf16)bv5.x; r1[5] = (__bf16)bv5.y;
    r0[6] = (__bf16)bv6.x; r1[6] = (__bf16)bv6.y;
    r0[7] = (__bf16)bv7.x; r1[7] = (__bf16)bv7.y;
    *(bf16x8*)(buf + bwOff) = r0;
    *(bf16x8*)(buf + bwOff + 64) = r1;
  };

  loadA(0);
  loadB(0);
  writeA(0);
  writeB(0);
  __syncthreads();

  for (int it = 0; it < NIT; ++it) {
    if (it + 1 < NIT) {
      loadA(it + 1);
      loadB(it + 1);
    }
    const unsigned short* cA = (const unsigned short*)lds[it & 1];
    const unsigned short* cB = cA + 4096;  // +8KB

    bf16x8 af[4], bfr[4];
#pragma unroll
    for (int mt = 0; mt < 4; ++mt)
      af[mt] =
          *(const bf16x8*)(cA + (wr * 64 + mt * 16 + lrow) * 32 + kslot * 8);
#pragma unroll
    for (int nt = 0; nt < 4; ++nt)
      bfr[nt] =
          *(const bf16x8*)(cB + (wc * 64 + nt * 16 + lrow) * 32 + kslot * 8);
#pragma unroll
    for (int mt = 0; mt < 4; ++mt)
#pragma unroll
      for (int nt = 0; nt < 4; ++nt)
        acc[mt][nt] = __builtin_amdgcn_mfma_f32_16x16x32_bf16(
            af[mt], bfr[nt], acc[mt][nt], 0, 0, 0);

    if (it + 1 < NIT) {
      writeA(it + 1);
      writeB(it + 1);
    }
    __syncthreads();
  }

  // C/D layout (verified m89/m91): col = lane&15, row = (lane>>4)*4 + reg
#pragma unroll
  for (int mt = 0; mt < 4; ++mt) {
    const int gmb = m0 + wr * 64 + mt * 16 + kb * 4;
#pragma unroll
    for (int nt = 0; nt < 4; ++nt) {
      const int gn = n0 + wc * 64 + nt * 16 + lrow;
      if (use_atomic) {
#pragma unroll
        for (int r = 0; r < 4; ++r)
          atomicAdd(out + (size_t)(gmb + r) * N_DIM + gn, acc[mt][nt][r]);
      } else {
        float* p = part + (size_t)z * PART_ELEMS;
#pragma unroll
        for (int r = 0; r < 4; ++r)
          p[(size_t)(gmb + r) * N_DIM + gn] = acc[mt][nt][r];
      }
    }
  }
}

// out = sum_z part[z] + bias ; 2048 blocks x 256 thr x 1 float4
__global__ __launch_bounds__(256) void reduce_kernel(
    const float* __restrict__ part, const float* __restrict__ bias,
    float* __restrict__ out) {
  const int g = blockIdx.x * 256 + threadIdx.x;  // [0, 524288)
  const float4* p = (const float4*)part;
  const float4* b4 = (const float4*)bias;
  const int Q = PART_ELEMS / 4;  // 524288
  float4 s0 = p[g];
  float4 s1 = p[g + Q];
  float4 s2 = p[g + 2 * Q];
  float4 s3 = p[g + 3 * Q];
  float4 bb = b4[g & (N_DIM / 4 - 1)];
  float4 r;
  r.x = s0.x + s1.x + s2.x + s3.x + bb.x;
  r.y = s0.y + s1.y + s2.y + s3.y + bb.y;
  r.z = s0.z + s1.z + s2.z + s3.z + bb.z;
  r.w = s0.w + s1.w + s2.w + s3.w + bb.w;
  ((float4*)out)[g] = r;
}

extern "C" void kernel_launch(void* const* d_in, const int* in_sizes, int n_in,
                              void* d_out, int out_size, void* d_ws,
                              size_t ws_size, hipStream_t stream) {
  const float* x = (const float*)d_in[0];     // [512, 4096]
  const float* w = (const float*)d_in[1];     // [512, 512, 8, 8]
  const float* bias = (const float*)d_in[2];  // [512, 8] -> flat col n
  float* out = (float*)d_out;                 // [512, 4096]

  float* part = (float*)d_ws;  // [0, 32MB): KSPLIT x 8MB fp32 partials

  const bool ws_ok = ws_size >= 32ull * 1024 * 1024;
  const int use_atomic = ws_ok ? 0 : 1;

  if (use_atomic)
    bias_init_kernel<<<PART_ELEMS / 4 / 256, 256, 0, stream>>>(bias, out);

  dim3 grid(N_DIM / 128, M_DIM / 128, KSPLIT);  // 32 x 4 x 4 = 512 blocks
  gemm_kernel<<<grid, 256, 0, stream>>>(x, w, out, part, use_atomic);

  if (!use_atomic)
    reduce_kernel<<<PART_ELEMS / 4 / 256, 256, 0, stream>>>(part, bias, out);
}

// Round 11
// 138.438 us; speedup vs baseline: 1.2745x; 1.2745x over previous
//
#include <hip/hip_runtime.h>
#include <stdint.h>

// OctonionLinear == GEMM: out[b, i*8+k] = sum_{j,p} x[b, j*8+p] * W[i,j,p,k] + bias[i,k]
// M=512, N=4096, K=4096, fp32 in/out, bf16 MFMA.
// R18 == R12 revert (verified best, 137.7us). Honors R15's pre-commit: fused
//  gemm measured 91.2us (>70 threshold) -> fusion refuted (latency-starved:
//  MfmaUtil 7%, scattered 8B W-loads, no global_load_lds). Ledger: all levers
//  measured -- wave-shape null (R7/R10), tile-occupancy null (R13), KSPLIT=8
//  -10us traffic (R14), fusion -6/-38 (R11/R17), swizzle +1.2 (R12).
// R12 = R10 structure + 2-way LDS slot-rotation swizzle (conflicts 4.19M->0):
//  KSPLIT=4, 128x128 tile, 4 waves of 64x64 (4x4 acc, 16 MFMA + 8 b128-reads
//  per barrier), 32KB dbuf, global_load_lds(16B) staging, part[4]+reduce
//  epilogue, atomic fallback if ws < 68MB.
// prep: W-transpose + x-convert; bias-init only in atomic fallback.

#define M_DIM 512
#define N_DIM 4096
#define K_DIM 4096
#define KSPLIT 4
#define KC (K_DIM / KSPLIT)                    // 1024
#define NIT (KC / 32)                          // 32
#define PART_ELEMS (M_DIM * N_DIM)             // 2097152 floats per z-slice

typedef __bf16 bf16x8 __attribute__((ext_vector_type(8)));
typedef float f32x4 __attribute__((ext_vector_type(4)));

__device__ inline unsigned short f2bf(float f) {
  union { float f; unsigned int u; } v;
  v.f = f;
  unsigned int u = v.u;
  unsigned int r = (u + 0x7fffu + ((u >> 16) & 1u)) >> 16;  // RNE
  return (unsigned short)r;
}

// blocks [0,4096): W transpose+convert -> bt[nn][kk], coalesced 16KB chunks.
// blocks [4096,5120): x convert -> abf, 8 el/thread.
// blocks [5120,7168): out = bias broadcast (ONLY launched in atomic path).
__global__ __launch_bounds__(256) void prep_kernel(
    const float* __restrict__ x, const float* __restrict__ w,
    const float* __restrict__ bias, unsigned short* __restrict__ abf,
    unsigned short* __restrict__ bt, float* __restrict__ out) {
  const int bid = blockIdx.x;
  const int t = threadIdx.x;
  if (bid < 4096) {
    __shared__ __align__(16) unsigned short lT[8][512];  // [k][j'*8+p], 8KB
    const int i = bid >> 3;
    const int jg = bid & 7;
    const float4* src =
        (const float4*)(w + (size_t)i * 32768 + jg * 4096 + t * 16);
    float4 v0 = src[0], v1 = src[1], v2 = src[2], v3 = src[3];
    const int jp = (t >> 2) * 8 + (t & 3) * 2;  // j'*8 + p0 (even)
    const float* lo = (const float*)&v0;  // k=0..3, p0   (v1: k=4..7)
    const float* hi = (const float*)&v2;  // k=0..3, p0+1 (v3: k=4..7)
#pragma unroll
    for (int k = 0; k < 4; ++k) {
      unsigned int pk =
          (unsigned int)f2bf(lo[k]) | ((unsigned int)f2bf(hi[k]) << 16);
      *(unsigned int*)&lT[k][jp] = pk;
    }
    lo = (const float*)&v1;
    hi = (const float*)&v3;
#pragma unroll
    for (int k = 0; k < 4; ++k) {
      unsigned int pk =
          (unsigned int)f2bf(lo[k]) | ((unsigned int)f2bf(hi[k]) << 16);
      *(unsigned int*)&lT[k + 4][jp] = pk;
    }
    __syncthreads();
    const int r = t >> 5, c = t & 31;  // 32B/thread, 1KB contiguous runs
    const uint4* s = (const uint4*)&lT[r][c * 16];
    uint4* d = (uint4*)(bt + (size_t)(i * 8 + r) * K_DIM + jg * 512 + c * 16);
    d[0] = s[0];
    d[1] = s[1];
  } else if (bid < 5120) {
    int g = (bid - 4096) * 256 + t;  // [0, 262144); 8 elements each
    const float4* xi = (const float4*)x;
    float4 a = xi[g * 2];
    float4 b = xi[g * 2 + 1];
    __attribute__((aligned(16))) unsigned short o[8] = {
        f2bf(a.x), f2bf(a.y), f2bf(a.z), f2bf(a.w),
        f2bf(b.x), f2bf(b.y), f2bf(b.z), f2bf(b.w)};
    *(uint4*)(abf + (size_t)g * 8) = *(const uint4*)o;
  } else {
    int g = (bid - 5120) * 256 + t;  // [0, 524288); 4 elements each
    int el = g * 4;
    int col = el & (N_DIM - 1);
    *(float4*)(out + el) = *(const float4*)(bias + col);
  }
}

__device__ inline void gld16(const void* g, void* l) {
  __builtin_amdgcn_global_load_lds(
      (const __attribute__((address_space(1))) unsigned int*)g,
      (__attribute__((address_space(3))) unsigned int*)l, 16, 0, 0);
}

// Tile 128M x 128N, BK=32, 256 threads = 4 waves, wave-tile 64M x 64N (4x4).
// LDS: A 128x32 (8KB) + B 128x32 (8KB) per buffer, dbuf = 32KB.
// Swizzled: LDS row r slot l (16B) holds global k-chunk g, l=(g+(r>>1))&3.
__global__ __launch_bounds__(256) void gemm_kernel(
    const unsigned short* __restrict__ A, const unsigned short* __restrict__ Bt,
    float* __restrict__ out, float* __restrict__ part, int use_atomic) {
  __shared__ __align__(16) char lds[2][16 * 1024];
  const int t = threadIdx.x;
  const int n0 = blockIdx.x * 128;
  const int m0 = blockIdx.y * 128;
  const int z = blockIdx.z;
  const int kc0 = z * KC;
  const int w = t >> 6;
  const int lane = t & 63;
  const int wr = w >> 1;     // 0..1 -> 64 M-rows
  const int wc = w & 1;      // 0..1 -> 64 N-cols
  const int lrow = lane & 15;
  const int kb = lane >> 4;  // k-block 0..3 (8 bf16 each)
  // swizzled read slot: lane-constant, 2-way bank aliasing (free, m136)
  const int kslot = (kb + (lrow >> 1)) & 3;

  f32x4 acc[4][4] = {};

  // staging: thread t -> LDS row r=t>>2 (within seg), linear slot l=t&3.
  // source global k-chunk g = (l - (r>>1)) & 3; (r>>1)&3 == (t>>3)&3 for both
  // segs (seg1 adds 64 rows = 32 to r>>1, 32%4==0).
  const int srow = t >> 2;  // 0..63
  const int gslot = ((t & 3) - ((t >> 3) & 3)) & 3;
  const int scol = gslot * 8;  // element col (16B-aligned)
  const size_t aOff0 = (size_t)(m0 + srow) * K_DIM + kc0 + scol;
  const size_t aOff1 = aOff0 + (size_t)64 * K_DIM;
  const size_t bOff0 = (size_t)(n0 + srow) * K_DIM + kc0 + scol;
  const size_t bOff1 = bOff0 + (size_t)64 * K_DIM;

  auto issue = [&](int it) {
    char* buf = lds[it & 1];
    gld16(A + aOff0 + it * 32, buf + t * 16);
    gld16(A + aOff1 + it * 32, buf + 4096 + t * 16);
    gld16(Bt + bOff0 + it * 32, buf + 8192 + t * 16);
    gld16(Bt + bOff1 + it * 32, buf + 12288 + t * 16);
  };

  issue(0);
  for (int it = 0; it < NIT; ++it) {
    __syncthreads();
    if (it + 1 < NIT) issue(it + 1);
    const unsigned short* cA = (const unsigned short*)lds[it & 1];
    const unsigned short* cB = cA + 4096;  // +8KB

    bf16x8 af[4], bfr[4];
#pragma unroll
    for (int mt = 0; mt < 4; ++mt)
      af[mt] =
          *(const bf16x8*)(cA + (wr * 64 + mt * 16 + lrow) * 32 + kslot * 8);
#pragma unroll
    for (int nt = 0; nt < 4; ++nt)
      bfr[nt] =
          *(const bf16x8*)(cB + (wc * 64 + nt * 16 + lrow) * 32 + kslot * 8);
#pragma unroll
    for (int mt = 0; mt < 4; ++mt)
#pragma unroll
      for (int nt = 0; nt < 4; ++nt)
        acc[mt][nt] = __builtin_amdgcn_mfma_f32_16x16x32_bf16(
            af[mt], bfr[nt], acc[mt][nt], 0, 0, 0);
  }

  // C/D layout (verified m89/m91): col = lane&15, row = (lane>>4)*4 + reg
#pragma unroll
  for (int mt = 0; mt < 4; ++mt) {
    const int gmb = m0 + wr * 64 + mt * 16 + kb * 4;
#pragma unroll
    for (int nt = 0; nt < 4; ++nt) {
      const int gn = n0 + wc * 64 + nt * 16 + lrow;
      if (use_atomic) {
#pragma unroll
        for (int r = 0; r < 4; ++r)
          atomicAdd(out + (size_t)(gmb + r) * N_DIM + gn, acc[mt][nt][r]);
      } else {
        float* p = part + (size_t)z * PART_ELEMS;
#pragma unroll
        for (int r = 0; r < 4; ++r)
          p[(size_t)(gmb + r) * N_DIM + gn] = acc[mt][nt][r];
      }
    }
  }
}

// out = sum_z part[z] + bias ; 2048 blocks x 256 thr x 1 float4
__global__ __launch_bounds__(256) void reduce_kernel(
    const float* __restrict__ part, const float* __restrict__ bias,
    float* __restrict__ out) {
  const int g = blockIdx.x * 256 + threadIdx.x;  // [0, 524288)
  const float4* p = (const float4*)part;
  const float4* b4 = (const float4*)bias;
  const int Q = PART_ELEMS / 4;  // 524288
  float4 s0 = p[g];
  float4 s1 = p[g + Q];
  float4 s2 = p[g + 2 * Q];
  float4 s3 = p[g + 3 * Q];
  float4 bb = b4[g & (N_DIM / 4 - 1)];
  float4 r;
  r.x = s0.x + s1.x + s2.x + s3.x + bb.x;
  r.y = s0.y + s1.y + s2.y + s3.y + bb.y;
  r.z = s0.z + s1.z + s2.z + s3.z + bb.z;
  r.w = s0.w + s1.w + s2.w + s3.w + bb.w;
  ((float4*)out)[g] = r;
}

extern "C" void kernel_launch(void* const* d_in, const int* in_sizes, int n_in,
                              void* d_out, int out_size, void* d_ws,
                              size_t ws_size, hipStream_t stream) {
  const float* x = (const float*)d_in[0];     // [512, 4096]
  const float* w = (const float*)d_in[1];     // [512, 512, 8, 8]
  const float* bias = (const float*)d_in[2];  // [512, 8]
  float* out = (float*)d_out;                 // [512, 4096]

  unsigned short* abf = (unsigned short*)d_ws;       // [0, 4MB) bf16 A
  unsigned short* bt = abf + (size_t)M_DIM * K_DIM;  // [4MB, 36MB) bf16 B^T
  float* part = (float*)((char*)d_ws + 36u * 1024 * 1024);  // [36MB, 68MB)

  const bool have_ws = ws_size >= 68ull * 1024 * 1024;
  const int use_atomic = have_ws ? 0 : 1;

  // bias-init segment only needed for the atomic path
  prep_kernel<<<use_atomic ? 7168 : 5120, 256, 0, stream>>>(x, w, bias, abf,
                                                            bt, out);

  dim3 grid(N_DIM / 128, M_DIM / 128, KSPLIT);  // 32 x 4 x 4 = 512 blocks
  gemm_kernel<<<grid, 256, 0, stream>>>(abf, bt, out, part, use_atomic);

  if (!use_atomic)
    reduce_kernel<<<PART_ELEMS / 4 / 256, 256, 0, stream>>>(part, bias, out);
}

// Round 12
// 137.050 us; speedup vs baseline: 1.2874x; 1.0101x over previous
//
#include <hip/hip_runtime.h>
#include <stdint.h>

// OctonionLinear == GEMM: out[b, i*8+k] = sum_{j,p} x[b, j*8+p] * W[i,j,p,k] + bias[i,k]
// M=512, N=4096, K=4096, fp32 in/out, bf16 MFMA.
// R19 = R12/R18 + BK=64 (one variable: halve barrier-drain events).
//  Gap to m97's 912 TF (same structure) = drain amortization: NIT 32->16.
//  Free here: grid is 512 blocks = 2 blocks/CU ALREADY grid-capped, so
//  64KB dbuf (2x64 <= 160KB/CU) costs no occupancy (m132's BK=128 regression
//  was an occupancy drop; we can't drop). Traffic unchanged, 0.5 rd/MFMA
//  unchanged. Swizzle -> 8 slots: row r slot l holds chunk g, l=(g+(r&7))&7;
//  2 lanes/slot within each 16-lane quarter (matches R12's measured 0).
//  Pre-commit: total >= 136 -> ROOFLINE declaration next round.
// prep: W-transpose + x-convert; bias-init only in atomic fallback.

#define M_DIM 512
#define N_DIM 4096
#define K_DIM 4096
#define KSPLIT 4
#define KC (K_DIM / KSPLIT)         // 1024
#define BK 64
#define NIT (KC / BK)               // 16
#define PART_ELEMS (M_DIM * N_DIM)  // 2097152 floats per z-slice

typedef __bf16 bf16x8 __attribute__((ext_vector_type(8)));
typedef float f32x4 __attribute__((ext_vector_type(4)));

__device__ inline unsigned short f2bf(float f) {
  union { float f; unsigned int u; } v;
  v.f = f;
  unsigned int u = v.u;
  unsigned int r = (u + 0x7fffu + ((u >> 16) & 1u)) >> 16;  // RNE
  return (unsigned short)r;
}

// blocks [0,4096): W transpose+convert -> bt[nn][kk], coalesced 16KB chunks.
// blocks [4096,5120): x convert -> abf, 8 el/thread.
// blocks [5120,7168): out = bias broadcast (ONLY launched in atomic path).
__global__ __launch_bounds__(256) void prep_kernel(
    const float* __restrict__ x, const float* __restrict__ w,
    const float* __restrict__ bias, unsigned short* __restrict__ abf,
    unsigned short* __restrict__ bt, float* __restrict__ out) {
  const int bid = blockIdx.x;
  const int t = threadIdx.x;
  if (bid < 4096) {
    __shared__ __align__(16) unsigned short lT[8][512];  // [k][j'*8+p], 8KB
    const int i = bid >> 3;
    const int jg = bid & 7;
    const float4* src =
        (const float4*)(w + (size_t)i * 32768 + jg * 4096 + t * 16);
    float4 v0 = src[0], v1 = src[1], v2 = src[2], v3 = src[3];
    const int jp = (t >> 2) * 8 + (t & 3) * 2;  // j'*8 + p0 (even)
    const float* lo = (const float*)&v0;  // k=0..3, p0   (v1: k=4..7)
    const float* hi = (const float*)&v2;  // k=0..3, p0+1 (v3: k=4..7)
#pragma unroll
    for (int k = 0; k < 4; ++k) {
      unsigned int pk =
          (unsigned int)f2bf(lo[k]) | ((unsigned int)f2bf(hi[k]) << 16);
      *(unsigned int*)&lT[k][jp] = pk;
    }
    lo = (const float*)&v1;
    hi = (const float*)&v3;
#pragma unroll
    for (int k = 0; k < 4; ++k) {
      unsigned int pk =
          (unsigned int)f2bf(lo[k]) | ((unsigned int)f2bf(hi[k]) << 16);
      *(unsigned int*)&lT[k + 4][jp] = pk;
    }
    __syncthreads();
    const int r = t >> 5, c = t & 31;  // 32B/thread, 1KB contiguous runs
    const uint4* s = (const uint4*)&lT[r][c * 16];
    uint4* d = (uint4*)(bt + (size_t)(i * 8 + r) * K_DIM + jg * 512 + c * 16);
    d[0] = s[0];
    d[1] = s[1];
  } else if (bid < 5120) {
    int g = (bid - 4096) * 256 + t;  // [0, 262144); 8 elements each
    const float4* xi = (const float4*)x;
    float4 a = xi[g * 2];
    float4 b = xi[g * 2 + 1];
    __attribute__((aligned(16))) unsigned short o[8] = {
        f2bf(a.x), f2bf(a.y), f2bf(a.z), f2bf(a.w),
        f2bf(b.x), f2bf(b.y), f2bf(b.z), f2bf(b.w)};
    *(uint4*)(abf + (size_t)g * 8) = *(const uint4*)o;
  } else {
    int g = (bid - 5120) * 256 + t;  // [0, 524288); 4 elements each
    int el = g * 4;
    int col = el & (N_DIM - 1);
    *(float4*)(out + el) = *(const float4*)(bias + col);
  }
}

__device__ inline void gld16(const void* g, void* l) {
  __builtin_amdgcn_global_load_lds(
      (const __attribute__((address_space(1))) unsigned int*)g,
      (__attribute__((address_space(3))) unsigned int*)l, 16, 0, 0);
}

// Tile 128M x 128N, BK=64, 256 threads = 4 waves, wave-tile 64M x 64N (4x4).
// LDS per buffer: A 128x64 bf16 (16KB) @0, B 128x64 (16KB) @16KB; dbuf 64KB.
// Swizzle: LDS row r slot l (16B = 8 bf16) holds k-chunk g, l=(g+(r&7))&7.
__global__ __launch_bounds__(256) void gemm_kernel(
    const unsigned short* __restrict__ A, const unsigned short* __restrict__ Bt,
    float* __restrict__ out, float* __restrict__ part, int use_atomic) {
  __shared__ __align__(16) char lds[2][32 * 1024];
  const int t = threadIdx.x;
  const int n0 = blockIdx.x * 128;
  const int m0 = blockIdx.y * 128;
  const int z = blockIdx.z;
  const int kc0 = z * KC;
  const int w = t >> 6;
  const int lane = t & 63;
  const int wr = w >> 1;     // 0..1 -> 64 M-rows
  const int wc = w & 1;      // 0..1 -> 64 N-cols
  const int lrow = lane & 15;
  const int kb = lane >> 4;  // k-block within an MFMA k=32 (8 bf16 each)

  f32x4 acc[4][4] = {};

  // staging: 4 A-segs + 4 B-segs of 16B per thread. Dest linear (rule #21):
  // buf + region + seg*4096 + t*16. Within a seg: row = seg*32 + (t>>3),
  // slot l = t&7. Source chunk g = (l - (row&7))&7 = ((t&7)-((t>>3)&7))&7
  // (seg*32 % 8 == 0).
  const int srow = t >> 3;  // 0..31 (row within segment)
  const int gslot = ((t & 7) - ((t >> 3) & 7)) & 7;
  const int scol = gslot * 8;  // element col (16B-aligned)
  size_t aOff[4], bOff[4];
#pragma unroll
  for (int s = 0; s < 4; ++s) {
    aOff[s] = (size_t)(m0 + s * 32 + srow) * K_DIM + kc0 + scol;
    bOff[s] = (size_t)(n0 + s * 32 + srow) * K_DIM + kc0 + scol;
  }

  auto issue = [&](int it) {
    char* buf = lds[it & 1];
#pragma unroll
    for (int s = 0; s < 4; ++s)
      gld16(A + aOff[s] + it * BK, buf + s * 4096 + t * 16);
#pragma unroll
    for (int s = 0; s < 4; ++s)
      gld16(Bt + bOff[s] + it * BK, buf + 16384 + s * 4096 + t * 16);
  };

  issue(0);
  for (int it = 0; it < NIT; ++it) {
    __syncthreads();
    if (it + 1 < NIT) issue(it + 1);
    const unsigned short* cA = (const unsigned short*)lds[it & 1];
    const unsigned short* cB = cA + 8192;  // +16KB

#pragma unroll
    for (int kk = 0; kk < 2; ++kk) {
      const int chunk = kk * 4 + kb;                 // 0..7
      const int slot = (chunk + (lrow & 7)) & 7;     // swizzled 16B slot
      bf16x8 af[4], bfr[4];
#pragma unroll
      for (int mt = 0; mt < 4; ++mt)
        af[mt] =
            *(const bf16x8*)(cA + (wr * 64 + mt * 16 + lrow) * 64 + slot * 8);
#pragma unroll
      for (int nt = 0; nt < 4; ++nt)
        bfr[nt] =
            *(const bf16x8*)(cB + (wc * 64 + nt * 16 + lrow) * 64 + slot * 8);
#pragma unroll
      for (int mt = 0; mt < 4; ++mt)
#pragma unroll
        for (int nt = 0; nt < 4; ++nt)
          acc[mt][nt] = __builtin_amdgcn_mfma_f32_16x16x32_bf16(
              af[mt], bfr[nt], acc[mt][nt], 0, 0, 0);
    }
  }

  // C/D layout (verified m89/m91): col = lane&15, row = (lane>>4)*4 + reg
#pragma unroll
  for (int mt = 0; mt < 4; ++mt) {
    const int gmb = m0 + wr * 64 + mt * 16 + kb * 4;
#pragma unroll
    for (int nt = 0; nt < 4; ++nt) {
      const int gn = n0 + wc * 64 + nt * 16 + lrow;
      if (use_atomic) {
#pragma unroll
        for (int r = 0; r < 4; ++r)
          atomicAdd(out + (size_t)(gmb + r) * N_DIM + gn, acc[mt][nt][r]);
      } else {
        float* p = part + (size_t)z * PART_ELEMS;
#pragma unroll
        for (int r = 0; r < 4; ++r)
          p[(size_t)(gmb + r) * N_DIM + gn] = acc[mt][nt][r];
      }
    }
  }
}

// out = sum_z part[z] + bias ; 2048 blocks x 256 thr x 1 float4
__global__ __launch_bounds__(256) void reduce_kernel(
    const float* __restrict__ part, const float* __restrict__ bias,
    float* __restrict__ out) {
  const int g = blockIdx.x * 256 + threadIdx.x;  // [0, 524288)
  const float4* p = (const float4*)part;
  const float4* b4 = (const float4*)bias;
  const int Q = PART_ELEMS / 4;  // 524288
  float4 s0 = p[g];
  float4 s1 = p[g + Q];
  float4 s2 = p[g + 2 * Q];
  float4 s3 = p[g + 3 * Q];
  float4 bb = b4[g & (N_DIM / 4 - 1)];
  float4 r;
  r.x = s0.x + s1.x + s2.x + s3.x + bb.x;
  r.y = s0.y + s1.y + s2.y + s3.y + bb.y;
  r.z = s0.z + s1.z + s2.z + s3.z + bb.z;
  r.w = s0.w + s1.w + s2.w + s3.w + bb.w;
  ((float4*)out)[g] = r;
}

extern "C" void kernel_launch(void* const* d_in, const int* in_sizes, int n_in,
                              void* d_out, int out_size, void* d_ws,
                              size_t ws_size, hipStream_t stream) {
  const float* x = (const float*)d_in[0];     // [512, 4096]
  const float* w = (const float*)d_in[1];     // [512, 512, 8, 8]
  const float* bias = (const float*)d_in[2];  // [512, 8]
  float* out = (float*)d_out;                 // [512, 4096]

  unsigned short* abf = (unsigned short*)d_ws;       // [0, 4MB) bf16 A
  unsigned short* bt = abf + (size_t)M_DIM * K_DIM;  // [4MB, 36MB) bf16 B^T
  float* part = (float*)((char*)d_ws + 36u * 1024 * 1024);  // [36MB, 68MB)

  const bool have_ws = ws_size >= 68ull * 1024 * 1024;
  const int use_atomic = have_ws ? 0 : 1;

  // bias-init segment only needed for the atomic path
  prep_kernel<<<use_atomic ? 7168 : 5120, 256, 0, stream>>>(x, w, bias, abf,
                                                            bt, out);

  dim3 grid(N_DIM / 128, M_DIM / 128, KSPLIT);  // 32 x 4 x 4 = 512 blocks
  gemm_kernel<<<grid, 256, 0, stream>>>(abf, bt, out, part, use_atomic);

  if (!use_atomic)
    reduce_kernel<<<PART_ELEMS / 4 / 256, 256, 0, stream>>>(part, bias, out);
}